// Round 1
// 286.030 us; speedup vs baseline: 1.0442x; 1.0442x over previous
//
#include <hip/hip_runtime.h>
#include <cstdint>
#include <cstddef>

#define BB 64
#define PP 24564
#define OO 16
#define NC 21
#define TPB 256
#define GL 96    /* loss blocks per batch = ceil(PP/TPB) */
#define TPD 1024
#define NPT 24   /* ceil(PP/TPD) */

// match kernel geometry
#define MB 4
#define MT 1024
#define MPT 6    /* MB*MT*MPT = 24576 >= PP */

// ---------------- workspace layout (bytes), no memset needed ----------------
static constexpr size_t OFF_PB   = 0;        // u8  [BB*PP]      per-prior: bt|flag
static constexpr size_t OFF_LH   = 1572096;  // f32 [BB*PP]
static constexpr size_t OFF_KEYS = 7860480;  // u64 [BB*MB*OO]   per-block match keys
static constexpr size_t OFF_ALP  = 7893248;  // f32 [BB*GL]      loc partials
static constexpr size_t OFF_ACP  = 7917824;  // f32 [BB*GL]      conf-pos partials
static constexpr size_t OFF_NPP  = 7942400;  // i32 [BB*GL]      num_pos partials
static constexpr size_t OFF_NPT  = 7966976;  // i32 [BB]
static constexpr size_t OFF_TOPC = 7967232;  // f64 [BB]

// ---------------- Pass A: all IoUs once; per-truth keys + per-prior byte ----
__global__ __launch_bounds__(MT) void match_kernel(
    const float* __restrict__ priors, const float* __restrict__ targets,
    unsigned long long* __restrict__ keys_part, unsigned char* __restrict__ pb) {
  const int b = blockIdx.y, bx = blockIdx.x;
  __shared__ float ts[5][OO];  // x1,y1,x2,y2,area
  __shared__ unsigned long long red[OO * 16];
  if (threadIdx.x < OO) {
    const float* tg = targets + ((size_t)b * OO + threadIdx.x) * 5;
    float x1 = tg[0], y1 = tg[1], x2 = tg[2], y2 = tg[3];
    ts[0][threadIdx.x] = x1; ts[1][threadIdx.x] = y1;
    ts[2][threadIdx.x] = x2; ts[3][threadIdx.x] = y2;
    ts[4][threadIdx.x] = (x2 - x1) * (y2 - y1);
  }
  __syncthreads();

  // load my priors once (registers), truths read once per t (LDS broadcast)
  float ax1[MPT], ay1[MPT], ax2[MPT], ay2[MPT], ap[MPT];
  int pidx[MPT]; bool vld[MPT];
  #pragma unroll
  for (int i = 0; i < MPT; ++i) {
    int p = bx * MT + threadIdx.x + i * (MB * MT);
    vld[i] = (p < PP); pidx[i] = p;
    int pc = vld[i] ? p : 0;
    float4 pr = reinterpret_cast<const float4*>(priors)[pc];
    ax1[i] = pr.x - pr.z * 0.5f; ay1[i] = pr.y - pr.w * 0.5f;
    ax2[i] = pr.x + pr.z * 0.5f; ay2[i] = pr.y + pr.w * 0.5f;
    ap[i] = (ax2[i] - ax1[i]) * (ay2[i] - ay1[i]);
  }
  float pbest[MPT]; int pbt[MPT];
  #pragma unroll
  for (int i = 0; i < MPT; ++i) { pbest[i] = -1.f; pbt[i] = 0; }

  const int lane = threadIdx.x & 63, wid = threadIdx.x >> 6;
  #pragma unroll
  for (int t = 0; t < OO; ++t) {
    float tx1 = ts[0][t], ty1 = ts[1][t], tx2 = ts[2][t], ty2 = ts[3][t];
    float at = ts[4][t];
    unsigned long long kt = 0ull;
    #pragma unroll
    for (int i = 0; i < MPT; ++i) {
      float lx = fmaxf(tx1, ax1[i]), ly = fmaxf(ty1, ay1[i]);
      float rx = fminf(tx2, ax2[i]), ry = fminf(ty2, ay2[i]);
      float iw = fmaxf(rx - lx, 0.f), ih = fmaxf(ry - ly, 0.f);
      float inter = iw * ih;
      float iou = inter / (at + ap[i] - inter);  // precise div: argmax-exact
      unsigned long long key = ((unsigned long long)__float_as_uint(iou) << 32)
          | (unsigned long long)(0xFFFFFFFFu - (unsigned)pidx[i]);
      if (vld[i] && key > kt) kt = key;
      if (iou > pbest[i]) { pbest[i] = iou; pbt[i] = t; }  // first-max (argmax)
    }
    // block reduce this truth's best prior
    for (int off = 32; off; off >>= 1) {
      unsigned long long o = __shfl_down(kt, off, 64);
      if (o > kt) kt = o;
    }
    if (lane == 0) red[t * 16 + wid] = kt;
  }
  #pragma unroll
  for (int i = 0; i < MPT; ++i)
    if (vld[i])
      pb[(size_t)b * PP + pidx[i]] =
          (unsigned char)(pbt[i] | (pbest[i] >= 0.5f ? 16 : 0));
  __syncthreads();
  if (threadIdx.x < OO) {
    unsigned long long m = red[threadIdx.x * 16];
    #pragma unroll
    for (int w = 1; w < 16; ++w) {
      unsigned long long o = red[threadIdx.x * 16 + w];
      if (o > m) m = o;
    }
    keys_part[((size_t)b * MB + bx) * OO + threadIdx.x] = m;  // plain store
  }
}

// ---------------- Pass B: CE + smooth-L1 (match read from pb byte) ----------
__global__ __launch_bounds__(TPB) void loss_kernel(
    const float* __restrict__ loc, const float* __restrict__ conf,
    const float* __restrict__ priors, const float* __restrict__ targets,
    const unsigned long long* __restrict__ keys_part,
    const unsigned char* __restrict__ pb,
    float* __restrict__ lh, float* __restrict__ alp, float* __restrict__ acp,
    int* __restrict__ npp) {
  const int b = blockIdx.y;
  const int p0 = blockIdx.x * TPB;
  const int p = p0 + threadIdx.x;
  __shared__ float sc[TPB * NC];
  __shared__ float tcx[OO], tcy[OO], twd[OO], tht[OO];
  __shared__ int lab[OO], fp[OO];
  __shared__ float rc[TPB / 64], rl[TPB / 64];
  __shared__ int rn[TPB / 64];
  if (threadIdx.x < OO) {
    const float* tg = targets + ((size_t)b * OO + threadIdx.x) * 5;
    float x1 = tg[0], y1 = tg[1], x2 = tg[2], y2 = tg[3];
    tcx[threadIdx.x] = (x1 + x2) * 0.5f; tcy[threadIdx.x] = (y1 + y2) * 0.5f;
    twd[threadIdx.x] = x2 - x1; tht[threadIdx.x] = y2 - y1;
    lab[threadIdx.x] = (int)tg[4];
    unsigned long long k = keys_part[((size_t)b * MB) * OO + threadIdx.x];
    #pragma unroll
    for (int j = 1; j < MB; ++j) {
      unsigned long long o = keys_part[((size_t)b * MB + j) * OO + threadIdx.x];
      if (o > k) k = o;
    }
    unsigned pq = 0xFFFFFFFFu - (unsigned)(k & 0xFFFFFFFFu);
    fp[threadIdx.x] = (pq < PP) ? (int)pq : -1;
  }
  const int nvalid = min(TPB, PP - p0);
  {
    const float4* cb4 =
        reinterpret_cast<const float4*>(conf + ((size_t)b * PP + p0) * NC);
    float4* sc4 = reinterpret_cast<float4*>(sc);
    const int n4 = nvalid * NC / 4;  // exact: nvalid is 256 or 244
    for (int i = threadIdx.x; i < n4; i += TPB) sc4[i] = cb4[i];
  }
  __syncthreads();

  float ce = 0.f, l_part = 0.f;
  bool pos = false;
  if (p < PP) {
    unsigned m8 = pb[(size_t)b * PP + p];
    int t = (int)(m8 & 15u);
    bool sel = (m8 & 16u) != 0u;
    #pragma unroll
    for (int j = 0; j < OO; ++j)  // ascending, last-wins (matches scatter)
      if (fp[j] == p) { t = j; sel = true; }

    const float* cv = &sc[threadIdx.x * NC];
    float mx = cv[0];
    #pragma unroll
    for (int i = 1; i < NC; ++i) mx = fmaxf(mx, cv[i]);
    float s = 0.f;
    #pragma unroll
    for (int i = 0; i < NC; ++i) s += __expf(cv[i] - mx);
    float lse = mx + __logf(s);

    int c = sel ? (lab[t] + 1) : 0;
    ce = lse - cv[c];
    pos = sel;  // labels >= 0, so c>0 iff sel
    lh[(size_t)b * PP + p] = pos ? 0.f : fmaxf(ce, 0.f);  // keep bits >= 0

    if (pos) {
      float4 pr = reinterpret_cast<const float4*>(priors)[p];
      float gx = (tcx[t] - pr.x) / (0.1f * pr.z);
      float gy = (tcy[t] - pr.y) / (0.1f * pr.w);
      float gw = __logf(twd[t] / pr.z) / 0.2f;
      float gh = __logf(tht[t] / pr.w) / 0.2f;
      float4 lv = reinterpret_cast<const float4*>(loc)[(size_t)b * PP + p];
      float g[4] = {gx, gy, gw, gh};
      float l[4] = {lv.x, lv.y, lv.z, lv.w};
      #pragma unroll
      for (int i = 0; i < 4; ++i) {
        float d = l[i] - g[i];
        float ad = fabsf(d);
        l_part += (ad < 1.f) ? 0.5f * d * d : (ad - 0.5f);
      }
    }
  }

  float cp = pos ? ce : 0.f;
  int cw = (int)__popcll(__ballot(pos));  // wave count, no shuffle chain
  for (int off = 32; off; off >>= 1) {
    cp += __shfl_down(cp, off, 64);
    l_part += __shfl_down(l_part, off, 64);
  }
  const int lane = threadIdx.x & 63, wid = threadIdx.x >> 6;
  if (lane == 0) { rc[wid] = cp; rl[wid] = l_part; rn[wid] = cw; }
  __syncthreads();
  if (threadIdx.x == 0) {
    float cs = 0.f, ls = 0.f; int n = 0;
    for (int i = 0; i < TPB / 64; ++i) { cs += rc[i]; ls += rl[i]; n += rn[i]; }
    const int o = b * GL + blockIdx.x;
    alp[o] = ls; acp[o] = cs; npp[o] = n;  // plain stores, no atomics/memset
  }
}

// ---------------- Pass C: per-batch top-K sum (ballot counts, 1 barrier/iter)
__global__ __launch_bounds__(TPD) void topk_kernel(
    const float* __restrict__ lh, const int* __restrict__ npp,
    int* __restrict__ np_tot, double* __restrict__ topC) {
  const int b = blockIdx.x;
  const int lane = threadIdx.x & 63, wid = threadIdx.x >> 6;
  __shared__ int s_np;
  __shared__ int rcnt[2][16];
  __shared__ double rs[16];
  __shared__ int rg[16];
  if (threadIdx.x == 0) s_np = 0;
  __syncthreads();
  {
    int v = (threadIdx.x < GL) ? npp[b * GL + threadIdx.x] : 0;
    for (int off = 32; off; off >>= 1) v += __shfl_down(v, off, 64);
    if (lane == 0 && v) atomicAdd(&s_np, v);
  }
  __syncthreads();
  const int np = s_np;
  if (threadIdx.x == 0) np_tot[b] = np;
  const int K = min(3 * np, PP - 1);
  if (K <= 0) {
    if (threadIdx.x == 0) topC[b] = 0.0;
    return;
  }

  unsigned bits[NPT];
  const float* base = lh + (size_t)b * PP;
  #pragma unroll
  for (int i = 0; i < NPT; ++i) {
    int idx = threadIdx.x + i * TPD;
    bits[i] = (idx < PP) ? __float_as_uint(base[idx]) : 0u;
  }

  // largest T with count(bits >= T) >= K  → T = bits of K-th largest
  unsigned lo = 0u, hi = 0x7F800000u;
  int par = 0;
  while (lo < hi) {
    unsigned mid = lo + (hi - lo + 1) / 2;
    int c = 0;
    #pragma unroll
    for (int i = 0; i < NPT; ++i)
      c += (int)__popcll(__ballot(bits[i] >= mid));  // wave total, scalar
    if (lane == 0) rcnt[par][wid] = c;
    __syncthreads();
    int tot = 0;
    #pragma unroll
    for (int w = 0; w < 16; ++w) tot += rcnt[par][w];  // all threads, uniform
    if (tot >= K) lo = mid; else hi = mid - 1;
    par ^= 1;  // parity buffer: next iter's writes can't race slow readers
  }
  const unsigned Tk = lo;

  float s = 0.f; int cgt = 0;
  #pragma unroll
  for (int i = 0; i < NPT; ++i) {
    if (bits[i] > Tk) s += __uint_as_float(bits[i]);
    cgt += (int)__popcll(__ballot(bits[i] > Tk));
  }
  double sd = (double)s;
  for (int off = 32; off; off >>= 1) sd += __shfl_down(sd, off, 64);
  if (lane == 0) { rs[wid] = sd; rg[wid] = cgt; }
  __syncthreads();
  if (threadIdx.x == 0) {
    double S = 0.0; int CG = 0;
    for (int i = 0; i < 16; ++i) { S += rs[i]; CG += rg[i]; }
    topC[b] = S + (double)__uint_as_float(Tk) * (double)(K - CG);
  }
}

// ---------------- Pass D: finalize (sums all partials) ----------------------
__global__ __launch_bounds__(256) void final_kernel(
    const float* __restrict__ alp, const float* __restrict__ acp,
    const double* __restrict__ topC, const int* __restrict__ np_tot,
    float* __restrict__ out) {
  __shared__ double rsl[4], rsc[4];
  __shared__ int rn[4];
  double sl = 0.0, scd = 0.0; int n = 0;
  for (int i = threadIdx.x; i < BB * GL; i += 256) {
    sl += (double)alp[i];
    scd += (double)acp[i];
  }
  if (threadIdx.x < BB) { scd += topC[threadIdx.x]; n = np_tot[threadIdx.x]; }
  for (int off = 32; off; off >>= 1) {
    sl += __shfl_down(sl, off, 64);
    scd += __shfl_down(scd, off, 64);
    n += __shfl_down(n, off, 64);
  }
  const int lane = threadIdx.x & 63, wid = threadIdx.x >> 6;
  if (lane == 0) { rsl[wid] = sl; rsc[wid] = scd; rn[wid] = n; }
  __syncthreads();
  if (threadIdx.x == 0) {
    double SL = 0.0, SC = 0.0; int N = 0;
    for (int i = 0; i < 4; ++i) { SL += rsl[i]; SC += rsc[i]; N += rn[i]; }
    double Nd = (double)max(N, 1);
    out[0] = (float)(SL / Nd);
    out[1] = (float)(SC / Nd);
  }
}

extern "C" void kernel_launch(void* const* d_in, const int* in_sizes, int n_in,
                              void* d_out, int out_size, void* d_ws, size_t ws_size,
                              hipStream_t stream) {
  const float* loc     = (const float*)d_in[0];  // B*P*4
  const float* conf    = (const float*)d_in[1];  // B*P*21
  const float* priors  = (const float*)d_in[2];  // P*4
  const float* targets = (const float*)d_in[3];  // B*O*5
  float* out = (float*)d_out;

  char* ws = (char*)d_ws;
  unsigned char* pb = (unsigned char*)(ws + OFF_PB);
  float* lh = (float*)(ws + OFF_LH);
  unsigned long long* keys_part = (unsigned long long*)(ws + OFF_KEYS);
  float* alp = (float*)(ws + OFF_ALP);
  float* acp = (float*)(ws + OFF_ACP);
  int* npp = (int*)(ws + OFF_NPP);
  int* np_tot = (int*)(ws + OFF_NPT);
  double* topC = (double*)(ws + OFF_TOPC);

  dim3 gridM(MB, BB);
  match_kernel<<<gridM, MT, 0, stream>>>(priors, targets, keys_part, pb);
  dim3 gridL(GL, BB);
  loss_kernel<<<gridL, TPB, 0, stream>>>(loc, conf, priors, targets, keys_part,
                                         pb, lh, alp, acp, npp);
  topk_kernel<<<BB, TPD, 0, stream>>>(lh, npp, np_tot, topC);
  final_kernel<<<1, 256, 0, stream>>>(alp, acp, topC, np_tot, out);
}

// Round 2
// 281.601 us; speedup vs baseline: 1.0606x; 1.0157x over previous
//
#include <hip/hip_runtime.h>
#include <cstdint>
#include <cstddef>

#define BB 64
#define PP 24564
#define OO 16
#define NC 21
#define TPB 256
#define GL 96    /* loss blocks per batch = ceil(PP/TPB) */
#define TPD 1024
#define NPT 24   /* ceil(PP/TPD) */

// match kernel geometry
#define MB 4
#define MT 1024
#define MPT 6    /* MB*MT*MPT = 24576 >= PP */

// ---------------- workspace layout (bytes), no memset needed ----------------
static constexpr size_t OFF_PB   = 0;        // u8  [BB*PP]      per-prior: bt|flag
static constexpr size_t OFF_LH   = 1572096;  // f32 [BB*PP]
static constexpr size_t OFF_KEYS = 7860480;  // u64 [BB*MB*OO]   per-block match keys
static constexpr size_t OFF_ALP  = 7893248;  // f32 [BB*GL]      loc partials
static constexpr size_t OFF_ACP  = 7917824;  // f32 [BB*GL]      conf-pos partials
static constexpr size_t OFF_NPP  = 7942400;  // i32 [BB*GL]      num_pos partials
static constexpr size_t OFF_NPT  = 7966976;  // i32 [BB]
static constexpr size_t OFF_TOPC = 7967232;  // f64 [BB]
static constexpr size_t OFF_TKT  = 7967744;  // i32 ticket

// ---------------- Pass A: all IoUs once; per-truth keys + per-prior byte ----
__global__ __launch_bounds__(MT) void match_kernel(
    const float* __restrict__ priors, const float* __restrict__ targets,
    unsigned long long* __restrict__ keys_part, unsigned char* __restrict__ pb,
    int* __restrict__ ticket) {
  const int b = blockIdx.y, bx = blockIdx.x;
  if (bx == 0 && b == 0 && threadIdx.x == 0) *ticket = 0;  // for fused final
  __shared__ float ts[5][OO];  // x1,y1,x2,y2,area
  __shared__ unsigned long long red[OO * 16];
  if (threadIdx.x < OO) {
    const float* tg = targets + ((size_t)b * OO + threadIdx.x) * 5;
    float x1 = tg[0], y1 = tg[1], x2 = tg[2], y2 = tg[3];
    ts[0][threadIdx.x] = x1; ts[1][threadIdx.x] = y1;
    ts[2][threadIdx.x] = x2; ts[3][threadIdx.x] = y2;
    ts[4][threadIdx.x] = (x2 - x1) * (y2 - y1);
  }
  __syncthreads();

  // load my priors once (registers), truths read once per t (LDS broadcast)
  float ax1[MPT], ay1[MPT], ax2[MPT], ay2[MPT], ap[MPT];
  int pidx[MPT]; bool vld[MPT];
  #pragma unroll
  for (int i = 0; i < MPT; ++i) {
    int p = bx * MT + threadIdx.x + i * (MB * MT);
    vld[i] = (p < PP); pidx[i] = p;
    int pc = vld[i] ? p : 0;
    float4 pr = reinterpret_cast<const float4*>(priors)[pc];
    ax1[i] = pr.x - pr.z * 0.5f; ay1[i] = pr.y - pr.w * 0.5f;
    ax2[i] = pr.x + pr.z * 0.5f; ay2[i] = pr.y + pr.w * 0.5f;
    ap[i] = (ax2[i] - ax1[i]) * (ay2[i] - ay1[i]);
  }
  float pbest[MPT]; int pbt[MPT];
  #pragma unroll
  for (int i = 0; i < MPT; ++i) { pbest[i] = -1.f; pbt[i] = 0; }

  const int lane = threadIdx.x & 63, wid = threadIdx.x >> 6;
  #pragma unroll
  for (int t = 0; t < OO; ++t) {
    float tx1 = ts[0][t], ty1 = ts[1][t], tx2 = ts[2][t], ty2 = ts[3][t];
    float at = ts[4][t];
    unsigned long long kt = 0ull;
    #pragma unroll
    for (int i = 0; i < MPT; ++i) {
      float lx = fmaxf(tx1, ax1[i]), ly = fmaxf(ty1, ay1[i]);
      float rx = fminf(tx2, ax2[i]), ry = fminf(ty2, ay2[i]);
      float iw = fmaxf(rx - lx, 0.f), ih = fmaxf(ry - ly, 0.f);
      float inter = iw * ih;
      float iou = inter / (at + ap[i] - inter);  // precise div: argmax-exact
      unsigned long long key = ((unsigned long long)__float_as_uint(iou) << 32)
          | (unsigned long long)(0xFFFFFFFFu - (unsigned)pidx[i]);
      if (vld[i] && key > kt) kt = key;
      if (iou > pbest[i]) { pbest[i] = iou; pbt[i] = t; }  // first-max (argmax)
    }
    // block reduce this truth's best prior
    for (int off = 32; off; off >>= 1) {
      unsigned long long o = __shfl_down(kt, off, 64);
      if (o > kt) kt = o;
    }
    if (lane == 0) red[t * 16 + wid] = kt;
  }
  #pragma unroll
  for (int i = 0; i < MPT; ++i)
    if (vld[i])
      pb[(size_t)b * PP + pidx[i]] =
          (unsigned char)(pbt[i] | (pbest[i] >= 0.5f ? 16 : 0));
  __syncthreads();
  if (threadIdx.x < OO) {
    unsigned long long m = red[threadIdx.x * 16];
    #pragma unroll
    for (int w = 1; w < 16; ++w) {
      unsigned long long o = red[threadIdx.x * 16 + w];
      if (o > m) m = o;
    }
    keys_part[((size_t)b * MB + bx) * OO + threadIdx.x] = m;  // plain store
  }
}

// ---------------- Pass B: CE + smooth-L1 (conf read direct, no LDS stage) ---
__global__ __launch_bounds__(TPB) void loss_kernel(
    const float* __restrict__ loc, const float* __restrict__ conf,
    const float* __restrict__ priors, const float* __restrict__ targets,
    const unsigned long long* __restrict__ keys_part,
    const unsigned char* __restrict__ pb,
    float* __restrict__ lh, float* __restrict__ alp, float* __restrict__ acp,
    int* __restrict__ npp) {
  const int b = blockIdx.y;
  const int p0 = blockIdx.x * TPB;
  const int p = p0 + threadIdx.x;
  __shared__ float tcx[OO], tcy[OO], twd[OO], tht[OO];
  __shared__ int lab[OO], fp[OO];
  __shared__ float rc[TPB / 64], rl[TPB / 64];
  __shared__ int rn[TPB / 64];
  if (threadIdx.x < OO) {
    const float* tg = targets + ((size_t)b * OO + threadIdx.x) * 5;
    float x1 = tg[0], y1 = tg[1], x2 = tg[2], y2 = tg[3];
    tcx[threadIdx.x] = (x1 + x2) * 0.5f; tcy[threadIdx.x] = (y1 + y2) * 0.5f;
    twd[threadIdx.x] = x2 - x1; tht[threadIdx.x] = y2 - y1;
    lab[threadIdx.x] = (int)tg[4];
    unsigned long long k = keys_part[((size_t)b * MB) * OO + threadIdx.x];
    #pragma unroll
    for (int j = 1; j < MB; ++j) {
      unsigned long long o = keys_part[((size_t)b * MB + j) * OO + threadIdx.x];
      if (o > k) k = o;
    }
    unsigned pq = 0xFFFFFFFFu - (unsigned)(k & 0xFFFFFFFFu);
    fp[threadIdx.x] = (pq < PP) ? (int)pq : -1;
  }
  __syncthreads();

  float ce = 0.f, l_part = 0.f;
  bool pos = false;
  if (p < PP) {
    unsigned m8 = pb[(size_t)b * PP + p];
    int t = (int)(m8 & 15u);
    bool sel = (m8 & 16u) != 0u;
    #pragma unroll
    for (int j = 0; j < OO; ++j)  // ascending, last-wins (matches scatter)
      if (fp[j] == p) { t = j; sel = true; }

    const float* cv = conf + ((size_t)b * PP + p) * NC;
    float v[NC];
    #pragma unroll
    for (int i = 0; i < NC; ++i) v[i] = cv[i];  // per-wave: dense 5.4 KB span
    float mx = v[0];
    #pragma unroll
    for (int i = 1; i < NC; ++i) mx = fmaxf(mx, v[i]);
    float s = 0.f;
    #pragma unroll
    for (int i = 0; i < NC; ++i) s += __expf(v[i] - mx);
    float lse = mx + __logf(s);

    int c = sel ? (lab[t] + 1) : 0;
    ce = lse - cv[c];  // dynamic index -> single global load (L1 hit), not v[c]
    pos = sel;         // labels >= 0, so c>0 iff sel
    lh[(size_t)b * PP + p] = pos ? 0.f : fmaxf(ce, 0.f);  // keep bits >= 0

    if (pos) {
      float4 pr = reinterpret_cast<const float4*>(priors)[p];
      float gx = (tcx[t] - pr.x) / (0.1f * pr.z);
      float gy = (tcy[t] - pr.y) / (0.1f * pr.w);
      float gw = __logf(twd[t] / pr.z) / 0.2f;
      float gh = __logf(tht[t] / pr.w) / 0.2f;
      float4 lv = reinterpret_cast<const float4*>(loc)[(size_t)b * PP + p];
      float g[4] = {gx, gy, gw, gh};
      float l[4] = {lv.x, lv.y, lv.z, lv.w};
      #pragma unroll
      for (int i = 0; i < 4; ++i) {
        float d = l[i] - g[i];
        float ad = fabsf(d);
        l_part += (ad < 1.f) ? 0.5f * d * d : (ad - 0.5f);
      }
    }
  }

  float cp = pos ? ce : 0.f;
  int cw = (int)__popcll(__ballot(pos));  // wave count, no shuffle chain
  for (int off = 32; off; off >>= 1) {
    cp += __shfl_down(cp, off, 64);
    l_part += __shfl_down(l_part, off, 64);
  }
  const int lane = threadIdx.x & 63, wid = threadIdx.x >> 6;
  if (lane == 0) { rc[wid] = cp; rl[wid] = l_part; rn[wid] = cw; }
  __syncthreads();
  if (threadIdx.x == 0) {
    float cs = 0.f, ls = 0.f; int n = 0;
    for (int i = 0; i < TPB / 64; ++i) { cs += rc[i]; ls += rl[i]; n += rn[i]; }
    const int o = b * GL + blockIdx.x;
    alp[o] = ls; acp[o] = cs; npp[o] = n;  // plain stores, no atomics/memset
  }
}

// ------- Pass C: per-batch top-K sum + fused grid finalize (ticket) ---------
__global__ __launch_bounds__(TPD) void topk_kernel(
    const float* __restrict__ lh, const int* __restrict__ npp,
    const float* __restrict__ alp, const float* __restrict__ acp,
    int* __restrict__ np_tot, double* __restrict__ topC,
    int* __restrict__ ticket, float* __restrict__ out) {
  const int b = blockIdx.x;
  const int lane = threadIdx.x & 63, wid = threadIdx.x >> 6;
  __shared__ int s_np;
  __shared__ int rcnt[2][16];
  __shared__ double rs[16];
  __shared__ int rg[16];
  if (threadIdx.x == 0) s_np = 0;
  __syncthreads();
  {
    int v = (threadIdx.x < GL) ? npp[b * GL + threadIdx.x] : 0;
    for (int off = 32; off; off >>= 1) v += __shfl_down(v, off, 64);
    if (lane == 0 && v) atomicAdd(&s_np, v);
  }
  __syncthreads();
  const int np = s_np;
  if (threadIdx.x == 0) np_tot[b] = np;
  const int K = min(3 * np, PP - 1);

  if (K > 0) {
    unsigned bits[NPT];
    const float* base = lh + (size_t)b * PP;
    #pragma unroll
    for (int i = 0; i < NPT; ++i) {
      int idx = threadIdx.x + i * TPD;
      bits[i] = (idx < PP) ? __float_as_uint(base[idx]) : 0u;
    }

    // largest T with count(bits >= T) >= K  → T = bits of K-th largest
    unsigned lo = 0u, hi = 0x7F800000u;
    int par = 0;
    while (lo < hi) {
      unsigned mid = lo + (hi - lo + 1) / 2;
      int c = 0;
      #pragma unroll
      for (int i = 0; i < NPT; ++i)
        c += (int)__popcll(__ballot(bits[i] >= mid));  // wave total, scalar
      if (lane == 0) rcnt[par][wid] = c;
      __syncthreads();
      int tot = 0;
      #pragma unroll
      for (int w = 0; w < 16; ++w) tot += rcnt[par][w];  // uniform broadcast
      if (tot >= K) lo = mid; else hi = mid - 1;
      par ^= 1;  // parity buffer: next iter's writes can't race slow readers
    }
    const unsigned Tk = lo;

    float s = 0.f; int cgt = 0;
    #pragma unroll
    for (int i = 0; i < NPT; ++i) {
      if (bits[i] > Tk) s += __uint_as_float(bits[i]);
      cgt += (int)__popcll(__ballot(bits[i] > Tk));
    }
    double sd = (double)s;
    for (int off = 32; off; off >>= 1) sd += __shfl_down(sd, off, 64);
    if (lane == 0) { rs[wid] = sd; rg[wid] = cgt; }
    __syncthreads();
    if (threadIdx.x == 0) {
      double S = 0.0; int CG = 0;
      for (int i = 0; i < 16; ++i) { S += rs[i]; CG += rg[i]; }
      topC[b] = S + (double)__uint_as_float(Tk) * (double)(K - CG);
    }
  } else if (threadIdx.x == 0) {
    topC[b] = 0.0;
  }

  // -------- ticket: last block to finish does the global finalize ----------
  __shared__ int s_last;
  if (threadIdx.x == 0) {
    __threadfence();
    s_last = (atomicAdd(ticket, 1) == BB - 1) ? 1 : 0;
  }
  __syncthreads();
  if (!s_last) return;
  __threadfence();

  __shared__ double fsl[16], fsc[16];
  __shared__ int fnn[16];
  double sl = 0.0, scd = 0.0; int n = 0;
  for (int i = threadIdx.x; i < BB * GL; i += TPD) {
    sl += (double)alp[i];
    scd += (double)acp[i];
  }
  if (threadIdx.x < BB) { scd += topC[threadIdx.x]; n = np_tot[threadIdx.x]; }
  for (int off = 32; off; off >>= 1) {
    sl += __shfl_down(sl, off, 64);
    scd += __shfl_down(scd, off, 64);
    n += __shfl_down(n, off, 64);
  }
  if (lane == 0) { fsl[wid] = sl; fsc[wid] = scd; fnn[wid] = n; }
  __syncthreads();
  if (threadIdx.x == 0) {
    double SL = 0.0, SC = 0.0; int N = 0;
    for (int i = 0; i < 16; ++i) { SL += fsl[i]; SC += fsc[i]; N += fnn[i]; }
    double Nd = (double)max(N, 1);
    out[0] = (float)(SL / Nd);
    out[1] = (float)(SC / Nd);
  }
}

extern "C" void kernel_launch(void* const* d_in, const int* in_sizes, int n_in,
                              void* d_out, int out_size, void* d_ws, size_t ws_size,
                              hipStream_t stream) {
  const float* loc     = (const float*)d_in[0];  // B*P*4
  const float* conf    = (const float*)d_in[1];  // B*P*21
  const float* priors  = (const float*)d_in[2];  // P*4
  const float* targets = (const float*)d_in[3];  // B*O*5
  float* out = (float*)d_out;

  char* ws = (char*)d_ws;
  unsigned char* pb = (unsigned char*)(ws + OFF_PB);
  float* lh = (float*)(ws + OFF_LH);
  unsigned long long* keys_part = (unsigned long long*)(ws + OFF_KEYS);
  float* alp = (float*)(ws + OFF_ALP);
  float* acp = (float*)(ws + OFF_ACP);
  int* npp = (int*)(ws + OFF_NPP);
  int* np_tot = (int*)(ws + OFF_NPT);
  double* topC = (double*)(ws + OFF_TOPC);
  int* ticket = (int*)(ws + OFF_TKT);

  dim3 gridM(MB, BB);
  match_kernel<<<gridM, MT, 0, stream>>>(priors, targets, keys_part, pb, ticket);
  dim3 gridL(GL, BB);
  loss_kernel<<<gridL, TPB, 0, stream>>>(loc, conf, priors, targets, keys_part,
                                         pb, lh, alp, acp, npp);
  topk_kernel<<<BB, TPD, 0, stream>>>(lh, npp, alp, acp, np_tot, topC, ticket, out);
}